// Round 3
// baseline (706.623 us; speedup 1.0000x reference)
//
#include <hip/hip_runtime.h>
#include <hip/hip_cooperative_groups.h>

namespace cg = cooperative_groups;

#define N_TOTAL 16384
#define NODE_DIM 64
#define HIDDEN 128
#define NPG 2048
#define NGRAPH 8
#define MBLOCKS 1024
#define MTHREADS 256
#define MTOTAL (MBLOCKS * MTHREADS)   // 262144 threads, 4096 waves

// ==================================================================
// Cooperative mega-kernel: all phases in one launch, grid.sync between.
// Phase GEMMs: lane = row, row data in VGPRs (static unroll), W^T rows
// broadcast via wave-uniform loads. No LDS anywhere.
// ==================================================================
__global__ __launch_bounds__(256, 4) void mega(
    const float* __restrict__ x, const void* __restrict__ ei,
    const float* __restrict__ W1, const float* __restrict__ b1,
    const float* __restrict__ W2, const float* __restrict__ b2,
    const float* __restrict__ wlin, const float* __restrict__ blin,
    float* __restrict__ out, int E,
    float* __restrict__ s1, float* __restrict__ agg1, float* __restrict__ deg,
    float* __restrict__ s2, float* __restrict__ agg2,
    float* __restrict__ left, float* __restrict__ right,
    float* __restrict__ W1T, float* __restrict__ W2T,
    float* __restrict__ h1T, int* __restrict__ flag) {
    cg::grid_group grid = cg::this_grid();
    const int tid  = threadIdx.x;
    const int gt   = blockIdx.x * MTHREADS + tid;   // 0..262143
    const int wid  = gt >> 6;                       // 0..4095
    const int lane = tid & 63;

    // ---------------- P1: flag detect, W transposes, rowsum(x), zero state
    if (gt == 0) {
        const int* w = (const int*)ei;
        int nz = 0;
        for (int i = 0; i < 256; ++i) if (w[2 * i + 1] != 0) nz = 1;
        *flag = nz;   // 1 => int32 layout, 0 => int64 layout
    }
    if (gt < NODE_DIM * HIDDEN) {               // W1T[c][k] = W1[k][c]
        int k = gt >> 7, c = gt & 127;
        W1T[c * NODE_DIM + k] = W1[gt];
    } else if (gt < NODE_DIM * HIDDEN + HIDDEN * HIDDEN) {
        int t2 = gt - NODE_DIM * HIDDEN;        // W2T[c][k] = W2[k][c]
        int k = t2 >> 7, c = t2 & 127;
        W2T[c * HIDDEN + k] = W2[t2];
    }
    {   // rowsum x: each wave does 4 rows, 16 lanes per row
        int row = wid * 4 + (lane >> 4);
        int q   = lane & 15;
        float4 v = ((const float4*)x)[row * 16 + q];
        float sum = v.x + v.y + v.z + v.w;
        sum += __shfl_xor(sum, 1);
        sum += __shfl_xor(sum, 2);
        sum += __shfl_xor(sum, 4);
        sum += __shfl_xor(sum, 8);
        if (q == 0) {
            s1[row] = sum;
            agg1[row] = 0.f; deg[row] = 0.f;
            s2[row] = 0.f;  agg2[row] = 0.f;
            left[row] = 0.f; right[row] = 0.f;
        }
    }
    grid.sync();

    // ---------------- P2: edge scatter pass 1 (2 edges/thread), stash decode
    int e_s0, e_s1, e_d0, e_d1; bool e_ok0, e_ok1;
    {
        int f = *flag;
        int e0 = 2 * gt, e1 = 2 * gt + 1;
        e_ok0 = e0 < E; e_ok1 = e1 < E;
        e_s0 = e_s1 = e_d0 = e_d1 = 0;
        if (e_ok1) {
            if (!f) {   // int64
                int4 sv = ((const int4*)ei)[gt];
                const int4* dp = (const int4*)((const char*)ei + (size_t)E * 8);
                int4 dv = dp[gt];
                e_s0 = sv.x; e_s1 = sv.z; e_d0 = dv.x; e_d1 = dv.z;
            } else {    // int32
                int2 sv = ((const int2*)ei)[gt];
                const int2* dp = (const int2*)((const char*)ei + (size_t)E * 4);
                int2 dv = dp[gt];
                e_s0 = sv.x; e_s1 = sv.y; e_d0 = dv.x; e_d1 = dv.y;
            }
        } else if (e_ok0) {
            if (!f) {
                const long long* ep = (const long long*)ei;
                e_s0 = (int)ep[e0]; e_d0 = (int)ep[E + e0];
            } else {
                const int* ep = (const int*)ei;
                e_s0 = ep[e0]; e_d0 = ep[E + e0];
            }
        }
        if (e_ok0) { atomicAdd(&agg1[e_d0], s1[e_s0]); atomicAdd(&deg[e_d0], 1.f); }
        if (e_ok1) { atomicAdd(&agg1[e_d1], s1[e_s1]); atomicAdd(&deg[e_d1], 1.f); }
    }
    grid.sync();

    // ---------------- P3: layer1 -> h1T (transposed), s2 partial atomics
    {
        int rb = wid >> 4, cgp = wid & 15;      // 256 row-blocks x 16 col-groups
        int row = rb * 64 + lane;
        float4 xq[16];
        const float4* xr = (const float4*)(x + row * NODE_DIM);
        #pragma unroll
        for (int j = 0; j < 16; ++j) xq[j] = xr[j];
        float d  = deg[row];
        float ag = agg1[row] / (d > 0.f ? d : 1.f);
        float sp = 0.f;
        int c0 = cgp * 8;
        #pragma unroll
        for (int ci = 0; ci < 8; ++ci) {
            int c = __builtin_amdgcn_readfirstlane(c0 + ci);
            const float* wr = W1T + c * NODE_DIM;
            float acc = 0.f;
            #pragma unroll
            for (int j = 0; j < 16; ++j) {
                acc = fmaf(xq[j].x, wr[4 * j + 0], acc);
                acc = fmaf(xq[j].y, wr[4 * j + 1], acc);
                acc = fmaf(xq[j].z, wr[4 * j + 2], acc);
                acc = fmaf(xq[j].w, wr[4 * j + 3], acc);
            }
            float h = ag + acc + b1[c];
            h = h > 0.f ? h : 0.f;
            h1T[c * N_TOTAL + row] = h;        // coalesced store
            sp += h;
        }
        atomicAdd(&s2[row], sp);
    }
    grid.sync();

    // ---------------- P4: edge scatter pass 2 (reuse decoded indices)
    if (e_ok0) atomicAdd(&agg2[e_d0], s2[e_s0]);
    if (e_ok1) atomicAdd(&agg2[e_d1], s2[e_s1]);
    grid.sync();

    // ---------------- P5: layer2 -> left/right partial atomics
    {
        int rb = wid >> 4, cgp = wid & 15;
        int row = rb * 64 + lane;
        float acc[8];
        #pragma unroll
        for (int ci = 0; ci < 8; ++ci) acc[ci] = 0.f;
        int c0 = cgp * 8;
        for (int kh = 0; kh < 2; ++kh) {
            float hq[64];
            const float* hb = h1T + (size_t)(kh * 64) * N_TOTAL + row;
            #pragma unroll
            for (int j = 0; j < 64; ++j) hq[j] = hb[(size_t)j * N_TOTAL];
            #pragma unroll
            for (int ci = 0; ci < 8; ++ci) {
                int c = __builtin_amdgcn_readfirstlane(c0 + ci);
                const float* wr = W2T + c * HIDDEN + kh * 64;
                float a = acc[ci];
                #pragma unroll
                for (int j = 0; j < 64; ++j) a = fmaf(hq[j], wr[j], a);
                acc[ci] = a;
            }
        }
        float d  = deg[row];
        float ag = agg2[row] / (d > 0.f ? d : 1.f);
        float lp = 0.f, rp = 0.f;
        #pragma unroll
        for (int ci = 0; ci < 8; ++ci) {
            int c = c0 + ci;
            float h = ag + acc[ci] + b2[c];
            h = h > 0.f ? h : 0.f;
            lp = fmaf(h, wlin[c], lp);
            rp = fmaf(h, wlin[HIDDEN + c], rp);
        }
        atomicAdd(&left[row], lp);
        atomicAdd(&right[row], rp);
    }
    grid.sync();

    // ---------------- P6: scores (write-bound, grid-stride float4)
    {
        const int total = NGRAPH * NPG * (NPG / 4);   // 8388608 float4s
        float bl = blin[0];
        for (int i = gt; i < total; i += MTOTAL) {
            int r  = i >> 9;
            int j4 = (i & 511) << 2;
            int b  = r >> 11;
            float L = left[r] + bl;
            float4 rv = *(const float4*)(right + (b << 11) + j4);
            float4 o;
            o.x = 1.f / (1.f + __expf(-(L + rv.x)));
            o.y = 1.f / (1.f + __expf(-(L + rv.y)));
            o.z = 1.f / (1.f + __expf(-(L + rv.z)));
            o.w = 1.f / (1.f + __expf(-(L + rv.w)));
            *(float4*)(out + ((size_t)r << 11) + j4) = o;
        }
    }
}

// ==================================================================
// Fallback path (round-2 kernels) in case cooperative launch fails.
// ==================================================================
__global__ __launch_bounds__(256) void k1_rowsum64(
    const float* __restrict__ x, float* __restrict__ s,
    float* __restrict__ agg1, float* __restrict__ deg,
    const int* __restrict__ ei_words, int* __restrict__ flag) {
    if (blockIdx.x == 0 && threadIdx.x == 0) {
        int odd_nonzero = 0;
        for (int i = 0; i < 256; ++i)
            if (ei_words[2 * i + 1] != 0) odd_nonzero = 1;
        *flag = odd_nonzero;
    }
    int row  = blockIdx.x * 4 + (threadIdx.x >> 6);
    int lane = threadIdx.x & 63;
    float v = x[row * NODE_DIM + lane];
    for (int off = 32; off; off >>= 1) v += __shfl_xor(v, off);
    if (lane == 0) { s[row] = v; agg1[row] = 0.f; deg[row] = 0.f; }
}

__global__ __launch_bounds__(256) void k_edge(
    const void* __restrict__ ei_raw, int E, const int* __restrict__ flag,
    const float* __restrict__ s, float* __restrict__ agg,
    float* __restrict__ deg) {
    int e = blockIdx.x * blockDim.x + threadIdx.x;
    if (e >= E) return;
    int sidx, didx;
    if (*flag) {
        const int* ei = (const int*)ei_raw;
        sidx = ei[e]; didx = ei[E + e];
    } else {
        const long long* ei = (const long long*)ei_raw;
        sidx = (int)ei[e]; didx = (int)ei[E + e];
    }
    atomicAdd(&agg[didx], s[sidx]);
    if (deg) atomicAdd(&deg[didx], 1.0f);
}

__global__ __launch_bounds__(256) void k3_layer1(
    const float* __restrict__ x, const float* __restrict__ W1,
    const float* __restrict__ b1, const float* __restrict__ agg1,
    const float* __restrict__ deg, float* __restrict__ h1,
    float* __restrict__ s2, float* __restrict__ agg2) {
    __shared__ float W1s[NODE_DIM * HIDDEN];
    __shared__ float xs[16 * NODE_DIM];
    int tid  = threadIdx.x;
    int base = blockIdx.x * 16;
    {
        const float4* Wv = (const float4*)W1;
        float4* Wsv = (float4*)W1s;
        for (int i = tid; i < NODE_DIM * HIDDEN / 4; i += 256) Wsv[i] = Wv[i];
        const float4* xv = (const float4*)(x + base * NODE_DIM);
        float4* xsv = (float4*)xs;
        for (int i = tid; i < 16 * NODE_DIM / 4; i += 256) xsv[i] = xv[i];
    }
    __syncthreads();
    int lane32 = tid & 31;
    int rg     = tid >> 5;
    int c4     = lane32 * 4;
    int row0   = rg * 2, row1 = rg * 2 + 1;
    float a00 = 0.f, a01 = 0.f, a02 = 0.f, a03 = 0.f;
    float a10 = 0.f, a11 = 0.f, a12 = 0.f, a13 = 0.f;
    #pragma unroll
    for (int k = 0; k < NODE_DIM; ++k) {
        float4 w = *(const float4*)&W1s[k * HIDDEN + c4];
        float x0 = xs[row0 * NODE_DIM + k];
        float x1 = xs[row1 * NODE_DIM + k];
        a00 = fmaf(x0, w.x, a00); a01 = fmaf(x0, w.y, a01);
        a02 = fmaf(x0, w.z, a02); a03 = fmaf(x0, w.w, a03);
        a10 = fmaf(x1, w.x, a10); a11 = fmaf(x1, w.y, a11);
        a12 = fmaf(x1, w.z, a12); a13 = fmaf(x1, w.w, a13);
    }
    float4 bb = *(const float4*)&b1[c4];
    {
        int grow = base + row0;
        float d = deg[grow];
        float a = agg1[grow] / (d > 0.f ? d : 1.f);
        float4 v;
        v.x = fmaxf(a + a00 + bb.x, 0.f);
        v.y = fmaxf(a + a01 + bb.y, 0.f);
        v.z = fmaxf(a + a02 + bb.z, 0.f);
        v.w = fmaxf(a + a03 + bb.w, 0.f);
        *(float4*)&h1[grow * HIDDEN + c4] = v;
        float rs = v.x + v.y + v.z + v.w;
        for (int off = 16; off; off >>= 1) rs += __shfl_xor(rs, off);
        if (lane32 == 0) { s2[grow] = rs; agg2[grow] = 0.f; }
    }
    {
        int grow = base + row1;
        float d = deg[grow];
        float a = agg1[grow] / (d > 0.f ? d : 1.f);
        float4 v;
        v.x = fmaxf(a + a10 + bb.x, 0.f);
        v.y = fmaxf(a + a11 + bb.y, 0.f);
        v.z = fmaxf(a + a12 + bb.z, 0.f);
        v.w = fmaxf(a + a13 + bb.w, 0.f);
        *(float4*)&h1[grow * HIDDEN + c4] = v;
        float rs = v.x + v.y + v.z + v.w;
        for (int off = 16; off; off >>= 1) rs += __shfl_xor(rs, off);
        if (lane32 == 0) { s2[grow] = rs; agg2[grow] = 0.f; }
    }
}

__global__ __launch_bounds__(256) void k6_layer2(
    const float* __restrict__ h1, const float* __restrict__ W2,
    const float* __restrict__ b2, const float* __restrict__ agg2,
    const float* __restrict__ deg, const float* __restrict__ wlin,
    float* __restrict__ left, float* __restrict__ right) {
    __shared__ float W2s[64 * HIDDEN];
    __shared__ float hs[16 * HIDDEN];
    int tid  = threadIdx.x;
    int base = blockIdx.x * 16;
    {
        const float4* hv = (const float4*)(h1 + base * HIDDEN);
        float4* hsv = (float4*)hs;
        for (int i = tid; i < 16 * HIDDEN / 4; i += 256) hsv[i] = hv[i];
    }
    int lane32 = tid & 31;
    int rg     = tid >> 5;
    int c4     = lane32 * 4;
    int row0   = rg * 2, row1 = rg * 2 + 1;
    float a00 = 0.f, a01 = 0.f, a02 = 0.f, a03 = 0.f;
    float a10 = 0.f, a11 = 0.f, a12 = 0.f, a13 = 0.f;
    for (int chunk = 0; chunk < 2; ++chunk) {
        __syncthreads();
        {
            const float4* Wv = (const float4*)(W2 + chunk * 64 * HIDDEN);
            float4* Wsv = (float4*)W2s;
            for (int i = tid; i < 64 * HIDDEN / 4; i += 256) Wsv[i] = Wv[i];
        }
        __syncthreads();
        int kb = chunk * 64;
        #pragma unroll 8
        for (int k = 0; k < 64; ++k) {
            float4 w = *(const float4*)&W2s[k * HIDDEN + c4];
            float h0 = hs[row0 * HIDDEN + kb + k];
            float h1v = hs[row1 * HIDDEN + kb + k];
            a00 = fmaf(h0, w.x, a00);  a01 = fmaf(h0, w.y, a01);
            a02 = fmaf(h0, w.z, a02);  a03 = fmaf(h0, w.w, a03);
            a10 = fmaf(h1v, w.x, a10); a11 = fmaf(h1v, w.y, a11);
            a12 = fmaf(h1v, w.z, a12); a13 = fmaf(h1v, w.w, a13);
        }
    }
    float4 bb  = *(const float4*)&b2[c4];
    float4 wl  = *(const float4*)&wlin[c4];
    float4 wr  = *(const float4*)&wlin[HIDDEN + c4];
    {
        int grow = base + row0;
        float d  = deg[grow];
        float ag = agg2[grow] / (d > 0.f ? d : 1.f);
        float h0 = fmaxf(ag + a00 + bb.x, 0.f);
        float h1e = fmaxf(ag + a01 + bb.y, 0.f);
        float h2e = fmaxf(ag + a02 + bb.z, 0.f);
        float h3e = fmaxf(ag + a03 + bb.w, 0.f);
        float lp = h0 * wl.x + h1e * wl.y + h2e * wl.z + h3e * wl.w;
        float rp = h0 * wr.x + h1e * wr.y + h2e * wr.z + h3e * wr.w;
        for (int off = 16; off; off >>= 1) {
            lp += __shfl_xor(lp, off);
            rp += __shfl_xor(rp, off);
        }
        if (lane32 == 0) { left[grow] = lp; right[grow] = rp; }
    }
    {
        int grow = base + row1;
        float d  = deg[grow];
        float ag = agg2[grow] / (d > 0.f ? d : 1.f);
        float h0 = fmaxf(ag + a10 + bb.x, 0.f);
        float h1e = fmaxf(ag + a11 + bb.y, 0.f);
        float h2e = fmaxf(ag + a12 + bb.z, 0.f);
        float h3e = fmaxf(ag + a13 + bb.w, 0.f);
        float lp = h0 * wl.x + h1e * wl.y + h2e * wl.z + h3e * wl.w;
        float rp = h0 * wr.x + h1e * wr.y + h2e * wr.z + h3e * wr.w;
        for (int off = 16; off; off >>= 1) {
            lp += __shfl_xor(lp, off);
            rp += __shfl_xor(rp, off);
        }
        if (lane32 == 0) { left[grow] = lp; right[grow] = rp; }
    }
}

__global__ __launch_bounds__(256) void k7_scores(
    const float* __restrict__ left, const float* __restrict__ right,
    const float* __restrict__ blin, float* __restrict__ out) {
    int t  = blockIdx.x * blockDim.x + threadIdx.x;
    int r  = t >> 9;
    int j4 = (t & 511) << 2;
    int b  = r >> 11;
    float L = left[r] + blin[0];
    float4 rv = *reinterpret_cast<const float4*>(&right[(b << 11) + j4]);
    float4 o;
    o.x = 1.f / (1.f + __expf(-(L + rv.x)));
    o.y = 1.f / (1.f + __expf(-(L + rv.y)));
    o.z = 1.f / (1.f + __expf(-(L + rv.z)));
    o.w = 1.f / (1.f + __expf(-(L + rv.w)));
    *reinterpret_cast<float4*>(&out[(r << 11) + j4]) = o;
}

// ==================================================================
extern "C" void kernel_launch(void* const* d_in, const int* in_sizes, int n_in,
                              void* d_out, int out_size, void* d_ws, size_t ws_size,
                              hipStream_t stream) {
    const float* x    = (const float*)d_in[0];
    const void*  ei   = d_in[1];
    const float* W1   = (const float*)d_in[2];
    const float* b1   = (const float*)d_in[3];
    const float* W2   = (const float*)d_in[4];
    const float* b2   = (const float*)d_in[5];
    const float* wlin = (const float*)d_in[6];
    const float* blin = (const float*)d_in[7];
    int E = in_sizes[1] / 2;

    float* ws    = (float*)d_ws;
    float* s1    = ws;
    float* agg1  = ws + 1 * N_TOTAL;
    float* deg   = ws + 2 * N_TOTAL;
    float* s2    = ws + 3 * N_TOTAL;
    float* agg2  = ws + 4 * N_TOTAL;
    float* left  = ws + 5 * N_TOTAL;
    float* right = ws + 6 * N_TOTAL;
    float* W1T   = ws + 7 * N_TOTAL;                       // 8192
    float* W2T   = W1T + NODE_DIM * HIDDEN;                // 16384
    float* h1T   = W2T + HIDDEN * HIDDEN;                  // 128 * 16384
    int*   flag  = (int*)(h1T + (size_t)HIDDEN * N_TOTAL);
    float* out   = (float*)d_out;

    // --- cooperative mega-kernel path
    void* xa = (void*)x; void* eia = (void*)ei;
    void* W1a = (void*)W1; void* b1a = (void*)b1;
    void* W2a = (void*)W2; void* b2a = (void*)b2;
    void* wla = (void*)wlin; void* bla = (void*)blin;
    void* outa = (void*)out; int Ea = E;
    void* s1a = s1; void* agg1a = agg1; void* dega = deg;
    void* s2a = s2; void* agg2a = agg2; void* lefta = left; void* righta = right;
    void* W1Ta = W1T; void* W2Ta = W2T; void* h1Ta = h1T; void* flaga = flag;
    void* args[] = { &xa, &eia, &W1a, &b1a, &W2a, &b2a, &wla, &bla, &outa, &Ea,
                     &s1a, &agg1a, &dega, &s2a, &agg2a, &lefta, &righta,
                     &W1Ta, &W2Ta, &h1Ta, &flaga };
    hipError_t err = hipLaunchCooperativeKernel(
        (const void*)mega, dim3(MBLOCKS), dim3(MTHREADS), args, 0, stream);
    if (err == hipSuccess) return;

    // --- fallback: proven round-2 multi-kernel path
    float* h1 = h1T;   // reuse scratch (row-major here)
    k1_rowsum64<<<N_TOTAL / 4, 256, 0, stream>>>(x, s1, agg1, deg,
                                                 (const int*)ei, flag);
    k_edge<<<(E + 255) / 256, 256, 0, stream>>>(ei, E, flag, s1, agg1, deg);
    k3_layer1<<<N_TOTAL / 16, 256, 0, stream>>>(x, W1, b1, agg1, deg, h1, s2, agg2);
    k_edge<<<(E + 255) / 256, 256, 0, stream>>>(ei, E, flag, s2, agg2, nullptr);
    k6_layer2<<<N_TOTAL / 16, 256, 0, stream>>>(h1, W2, b2, agg2, deg, wlin, left, right);
    k7_scores<<<(N_TOTAL * (NPG / 4)) / 256, 256, 0, stream>>>(left, right, blin, out);
}